// Round 2
// baseline (179.997 us; speedup 1.0000x reference)
//
#include <hip/hip_runtime.h>
#include <cstdint>

// Problem constants: B=32, C=256, P=32, H=W=56
#define B_    32
#define C_    256
#define P_    32
#define HW_   3136
#define NSTEP 98          // k-steps of 32 (98*32 = 3136)

typedef __attribute__((ext_vector_type(8))) short  short8;   // 8 x bf16 (MFMA A/B frag)
typedef __attribute__((ext_vector_type(4))) float  floatx4;  // MFMA C/D frag + native f32x4

__device__ __forceinline__ unsigned short f2bf(float f) {
    // round-to-nearest-even f32 -> bf16
    union { float f; unsigned u; } v; v.f = f;
    unsigned r = v.u + 0x7fffu + ((v.u >> 16) & 1u);
    return (unsigned short)(r >> 16);
}

// ---------------------------------------------------------------------------
// Kernel 1: wpart[b,p,hw] = bf16( part[b,p,hw] * sigmoid(sum_p' part*w + b) )
// Two passes over p per thread (2nd pass L1/L2-hot). ~4 us. (unchanged)
// ---------------------------------------------------------------------------
__global__ __launch_bounds__(64) void wprep_kernel(
    const float* __restrict__ part, const float* __restrict__ conv_w,
    const float* __restrict__ conv_b, unsigned short* __restrict__ wpart)
{
    const int HW4 = HW_ / 4;                          // 784
    int i4 = blockIdx.x * 64 + threadIdx.x;           // over B*HW/4 = 25088
    if (i4 >= B_ * HW4) return;
    int b  = i4 / HW4;
    int hw = (i4 - b * HW4) * 4;

    const float* pb = part + (size_t)b * P_ * HW_ + hw;
    float bias = conv_b[0];
    float4 z = make_float4(bias, bias, bias, bias);
#pragma unroll
    for (int p = 0; p < P_; ++p) {
        float w = conv_w[p];
        float4 v = *(const float4*)(pb + (size_t)p * HW_);
        z.x += v.x * w; z.y += v.y * w; z.z += v.z * w; z.w += v.w * w;
    }
    float4 a;
    a.x = 1.0f / (1.0f + __expf(-z.x));
    a.y = 1.0f / (1.0f + __expf(-z.y));
    a.z = 1.0f / (1.0f + __expf(-z.z));
    a.w = 1.0f / (1.0f + __expf(-z.w));

    unsigned short* ob = wpart + (size_t)b * P_ * HW_ + hw;
#pragma unroll
    for (int p = 0; p < P_; ++p) {
        float4 v = *(const float4*)(pb + (size_t)p * HW_);   // L1/L2-hot reload
        ushort4 o;
        o.x = f2bf(v.x * a.x); o.y = f2bf(v.y * a.y);
        o.z = f2bf(v.z * a.z); o.w = f2bf(v.w * a.w);
        *(ushort4*)(ob + (size_t)p * HW_) = o;
    }
}

// ---------------------------------------------------------------------------
// Kernel 2: barrier-free streaming bf16-MFMA GEMM, v3b.
//   feats[b,p,c] = sum_k wpart[b,p,k] * x[b,c,k]
// v3 changes vs v2 (176us run):
//   * c-chunk 32 -> 16: grid = 512 blocks x 512 thr = 2 blocks/CU,
//     16 waves/CU (4/SIMD) -- 2x TLP for the scattered 16B load streams.
//     x HBM traffic stays exactly-once (each block owns disjoint c-rows).
//   * XCD-chunked bijective swizzle: XCD x owns batches [4x,4x+4) so its
//     wpart slice (4 x 200KB = 800KB) is L2-resident vs 6.4MB thrash.
//   * nontemporal loads on the x stream / nontemporal out stores, so the
//     103MB single-use x stream does not evict wpart from L2.
//     (v3b: use native ext_vector floatx4 -- HIP float4 is rejected by
//      __builtin_nontemporal_load.)
// Per wave: k-slice [wv*98/8,(wv+1)*98/8); per step: 2x b128 A-frags from
// wpart (L2-hot), 2x floatx4 x loads, 8 f2bf, 2 MFMA. No barriers in K-loop.
// Epilogue: single 16KB-LDS reduce over the 8 k-slice waves.
// ---------------------------------------------------------------------------
__global__ __launch_bounds__(512, 4) void gemm_stream3(
    const float* __restrict__ x,              // [B,C,HW] fp32
    const unsigned short* __restrict__ wpart, // [B,P,HW] bf16
    float* __restrict__ out)                  // [B, P*C]
{
    __shared__ float red[8][512];             // 16 KB

    // bijective XCD-chunked swizzle (512 % 8 == 0)
    const int orig = blockIdx.x;              // hw round-robins orig%8 -> XCD
    const int swz  = (orig & 7) * 64 + (orig >> 3);
    const int ct   = swz & 15;                // c-chunk 0..15
    const int b    = swz >> 4;                // batch: XCD x gets b in [4x,4x+4)
    const int c0   = ct * 16;

    const int tid  = threadIdx.x;
    const int wv   = tid >> 6;                // 0..7 : k-slice
    const int lane = tid & 63;
    const int qd   = lane >> 4;               // quad 0..3 -> k-offset qd*8
    const int r15  = lane & 15;               // row within 16

    const int t0 = wv * NSTEP / 8;
    const int t1 = (wv + 1) * NSTEP / 8;

    // lane-fixed base pointers (k advances by 32 floats per step)
    const float*          xr  = x + (size_t)b * C_ * HW_ + (size_t)(c0 + r15) * HW_ + qd * 8;
    const unsigned short* ar0 = wpart + (size_t)b * P_ * HW_ + (size_t)r15 * HW_ + qd * 8;
    const unsigned short* ar1 = ar0 + (size_t)16 * HW_;

    floatx4 acc0 = (floatx4)0.0f;             // p rows 0..15
    floatx4 acc1 = (floatx4)0.0f;             // p rows 16..31

#pragma unroll 4
    for (int t = t0; t < t1; ++t) {
        const int kb = t * 32;
        // A fragments: 16B contiguous per lane, L2-hot (XCD-resident wpart)
        short8 a0 = *(const short8*)(ar0 + kb);
        short8 a1 = *(const short8*)(ar1 + kb);
        // B fragments: 8 consecutive k floats of this lane's x-row, streamed
        floatx4 x0 = __builtin_nontemporal_load((const floatx4*)(xr + kb));
        floatx4 x1 = __builtin_nontemporal_load((const floatx4*)(xr + kb) + 1);
        short8 b0;
        b0[0] = (short)f2bf(x0[0]); b0[1] = (short)f2bf(x0[1]);
        b0[2] = (short)f2bf(x0[2]); b0[3] = (short)f2bf(x0[3]);
        b0[4] = (short)f2bf(x1[0]); b0[5] = (short)f2bf(x1[1]);
        b0[6] = (short)f2bf(x1[2]); b0[7] = (short)f2bf(x1[3]);

        acc0 = __builtin_amdgcn_mfma_f32_16x16x32_bf16(a0, b0, acc0, 0, 0, 0);
        acc1 = __builtin_amdgcn_mfma_f32_16x16x32_bf16(a1, b0, acc1, 0, 0, 0);
    }

    // ---- reduction across the 8 k-slice waves ----
    // D layout: p = (acc sel)*16 + qd*4 + rg, c-col = r15 ; local idx = p*16 + c
#pragma unroll
    for (int rg = 0; rg < 4; ++rg) {
        red[wv][(qd * 4 + rg) * 16 + r15]      = acc0[rg];
        red[wv][(16 + qd * 4 + rg) * 16 + r15] = acc1[rg];
    }
    __syncthreads();

    float s = 0.0f;
#pragma unroll
    for (int w = 0; w < 8; ++w) s += red[w][tid];
    const int p  = tid >> 4;                  // 0..31
    const int cl = tid & 15;                  // 0..15
    __builtin_nontemporal_store(s, &out[(size_t)b * (P_ * C_) + p * C_ + c0 + cl]);
}

extern "C" void kernel_launch(void* const* d_in, const int* in_sizes, int n_in,
                              void* d_out, int out_size, void* d_ws, size_t ws_size,
                              hipStream_t stream) {
    const float* x      = (const float*)d_in[0];
    const float* part   = (const float*)d_in[1];
    const float* conv_w = (const float*)d_in[2];
    const float* conv_b = (const float*)d_in[3];
    unsigned short* wpart = (unsigned short*)d_ws;   // [B,P,HW] bf16 = 6.4 MB

    wprep_kernel<<<dim3((B_ * (HW_ / 4) + 63) / 64), dim3(64), 0, stream>>>(
        part, conv_w, conv_b, wpart);

    gemm_stream3<<<dim3(512), dim3(512), 0, stream>>>(
        x, wpart, (float*)d_out);
}